// Round 1
// baseline (280.147 us; speedup 1.0000x reference)
//
#include <hip/hip_runtime.h>
#include <hip/hip_bf16.h>

// FramesPositionalEncoding
//   x:  (T=4096, B=32, C=300) f32
//   pe: (5000, 300) f32
//   text_duration: (B=32, W=128) i32
//   out[t][b][c] = x[t][b][c] + (t < total[b] ? pe[t - seg_start(b,t)][c] : 0)
// seg_start(b,t) = largest starts[b][w] <= t (starts non-decreasing, starts[0]=0).

#define T_LEN 4096
#define B_N 32
#define C_N 300
#define C4_N 75            // 300 floats = 75 float4
#define W_N 128
#define MAXLEN 5000

__global__ void pos_table_kernel(const int* __restrict__ dur,
                                 int* __restrict__ pos_tab) {
    __shared__ int s_dur[W_N];
    __shared__ int s_starts[W_N];
    __shared__ int s_total;
    const int b = blockIdx.x;
    const int tid = threadIdx.x;

    if (tid < W_N) s_dur[tid] = dur[b * W_N + tid];
    __syncthreads();
    if (tid == 0) {
        int run = 0;
        for (int w = 0; w < W_N; ++w) { s_starts[w] = run; run += s_dur[w]; }
        s_total = run;
    }
    __syncthreads();
    const int total = s_total;

    for (int t = tid; t < T_LEN; t += blockDim.x) {
        int pos;
        if (t >= total) {
            pos = -1;  // masked: out = x
        } else {
            // binary search: largest w with s_starts[w] <= t
            int lo = 0, hi = W_N - 1;
            #pragma unroll
            for (int it = 0; it < 7; ++it) {   // ceil(log2(128)) = 7
                int mid = (lo + hi + 1) >> 1;
                if (s_starts[mid] <= t) lo = mid; else hi = mid - 1;
            }
            int p = t - s_starts[lo];
            pos = min(max(p, 0), MAXLEN - 1);
        }
        pos_tab[t * B_N + b] = pos;  // indexed by row = t*B + b (matches x layout)
    }
}

__global__ void add_pe_kernel(const float4* __restrict__ x,
                              const float4* __restrict__ pe,
                              const int* __restrict__ pos_tab,
                              float4* __restrict__ out) {
    const int N4 = T_LEN * B_N * C4_N;  // 9,830,400
    const int stride = gridDim.x * blockDim.x;
    for (int i4 = blockIdx.x * blockDim.x + threadIdx.x; i4 < N4; i4 += stride) {
        int row = i4 / C4_N;           // compiler -> magic-number mul
        int c4  = i4 - row * C4_N;
        int pos = pos_tab[row];        // broadcast within a row; L1/L2 hit
        float4 v = x[i4];
        if (pos >= 0) {
            float4 p = pe[pos * C4_N + c4];
            v.x += p.x; v.y += p.y; v.z += p.z; v.w += p.w;
        }
        out[i4] = v;
    }
}

extern "C" void kernel_launch(void* const* d_in, const int* in_sizes, int n_in,
                              void* d_out, int out_size, void* d_ws, size_t ws_size,
                              hipStream_t stream) {
    const float* x  = (const float*)d_in[0];
    const float* pe = (const float*)d_in[1];
    const int* dur  = (const int*)d_in[2];
    // d_in[3] = train scalar, unused by the reference math

    int* pos_tab = (int*)d_ws;  // T_LEN * B_N ints = 512 KB

    pos_table_kernel<<<B_N, 256, 0, stream>>>(dur, pos_tab);

    add_pe_kernel<<<2048, 256, 0, stream>>>(
        (const float4*)x, (const float4*)pe, pos_tab, (float4*)d_out);
}

// Round 5
// 268.371 us; speedup vs baseline: 1.0439x; 1.0439x over previous
//
#include <hip/hip_runtime.h>
#include <hip/hip_bf16.h>

// FramesPositionalEncoding
//   x:  (T=4096, B=32, C=300) f32
//   pe: (5000, 300) f32
//   text_duration: (B=32, W=128) i32
//   out[t][b][c] = x[t][b][c] + (t < total[b] ? pe[t - seg_start(b,t)][c] : 0)
// seg_start(b,t) = largest starts[b][w] <= t (starts non-decreasing, starts[0]=0).

#define T_LEN 4096
#define B_N 32
#define C_N 300
#define C4_N 75            // 300 floats = 75 float4
#define W_N 128
#define MAXLEN 5000
#define N4_TOTAL (T_LEN * B_N * C4_N)   // 9,830,400 = 9600 * 1024
#define ELEMS_PER_BLOCK 1024            // 256 threads x 4 float4
#define GRID_N (N4_TOTAL / ELEMS_PER_BLOCK)  // 9600, exact

// Native vector type — __builtin_nontemporal_* accepts these (HIP_vector_type is rejected).
typedef float f32x4 __attribute__((ext_vector_type(4)));

__global__ void pos_table_kernel(const int* __restrict__ dur,
                                 int* __restrict__ pos_tab) {
    __shared__ int s_dur[W_N];
    __shared__ int s_starts[W_N];
    __shared__ int s_total;
    const int b = blockIdx.x;
    const int tid = threadIdx.x;

    if (tid < W_N) s_dur[tid] = dur[b * W_N + tid];
    __syncthreads();
    if (tid == 0) {
        int run = 0;
        for (int w = 0; w < W_N; ++w) { s_starts[w] = run; run += s_dur[w]; }
        s_total = run;
    }
    __syncthreads();
    const int total = s_total;

    for (int t = tid; t < T_LEN; t += blockDim.x) {
        int pos;
        if (t >= total) {
            pos = -1;  // masked: out = x
        } else {
            // binary search: largest w with s_starts[w] <= t
            int lo = 0, hi = W_N - 1;
            #pragma unroll
            for (int it = 0; it < 7; ++it) {   // ceil(log2(128)) = 7
                int mid = (lo + hi + 1) >> 1;
                if (s_starts[mid] <= t) lo = mid; else hi = mid - 1;
            }
            int p = t - s_starts[lo];
            pos = min(max(p, 0), MAXLEN - 1);
        }
        pos_tab[t * B_N + b] = pos;  // indexed by row = t*B + b (matches x layout)
    }
}

__global__ __launch_bounds__(256) void add_pe_kernel(
        const f32x4* __restrict__ x,
        const f32x4* __restrict__ pe,
        const int* __restrict__ pos_tab,
        f32x4* __restrict__ out) {
    const int base = blockIdx.x * ELEMS_PER_BLOCK + threadIdx.x;

    int   idx[4];
    int   pos[4];
    int   c4 [4];
    f32x4 xv [4];

    // Batch the independent loads: 4 outstanding x-streams + 4 pos loads.
    #pragma unroll
    for (int k = 0; k < 4; ++k) {
        idx[k] = base + k * 256;
        int row = idx[k] / C4_N;           // const divide -> magic mul
        c4[k]  = idx[k] - row * C4_N;
        pos[k] = pos_tab[row];             // row-broadcast, cache-hit
        xv[k]  = __builtin_nontemporal_load(&x[idx[k]]);  // streamed once
    }

    #pragma unroll
    for (int k = 0; k < 4; ++k) {
        f32x4 v = xv[k];
        if (pos[k] >= 0) {
            v += pe[pos[k] * C4_N + c4[k]];   // keep pe cacheable (L2-resident)
        }
        __builtin_nontemporal_store(v, &out[idx[k]]);     // streamed once
    }
}

extern "C" void kernel_launch(void* const* d_in, const int* in_sizes, int n_in,
                              void* d_out, int out_size, void* d_ws, size_t ws_size,
                              hipStream_t stream) {
    const float* x  = (const float*)d_in[0];
    const float* pe = (const float*)d_in[1];
    const int* dur  = (const int*)d_in[2];
    // d_in[3] = train scalar, unused by the reference math

    int* pos_tab = (int*)d_ws;  // T_LEN * B_N ints = 512 KB

    pos_table_kernel<<<B_N, 256, 0, stream>>>(dur, pos_tab);

    add_pe_kernel<<<GRID_N, 256, 0, stream>>>(
        (const f32x4*)x, (const f32x4*)pe, pos_tab, (f32x4*)d_out);
}